// Round 1
// baseline (5583.689 us; speedup 1.0000x reference)
//
#include <hip/hip_runtime.h>

#define NODES 100000
#define EDGES 3200000
#define D 128

// ---------------- GEMM: h = x @ w (fp32 vector ALU; no fp32 MFMA on CDNA4) ---
// block = 256 threads (16 tx x 16 ty); tile = 64 rows x 128 cols;
// per-thread 4 rows x 8 cols. LDS: x-tile 64x129 (+1 pad) = 33 KB,
// w K-chunk 32x129 = 16.5 KB -> ~50 KB total, ~3 blocks/CU.
#define TM 64
#define XS_STRIDE 129
#define WS_STRIDE 129
#define KC 32

__global__ __launch_bounds__(256) void gemm_xw(const float* __restrict__ x,
                                               const float* __restrict__ w,
                                               float* __restrict__ h,
                                               int nrows) {
    __shared__ float xs[TM * XS_STRIDE];
    __shared__ float ws[KC * WS_STRIDE];
    const int tid = threadIdx.x;
    const int tx = tid & 15;   // col group: cols tx + 16*j
    const int ty = tid >> 4;   // row group: rows ty*4 + i
    const int row0 = blockIdx.x * TM;

    // stage x tile (coalesced: consecutive tid -> consecutive c)
    for (int i = tid; i < TM * D; i += 256) {
        int r = i >> 7;
        int c = i & 127;
        int gr = row0 + r;
        xs[r * XS_STRIDE + c] = (gr < nrows) ? x[(long)gr * D + c] : 0.f;
    }

    float acc[4][8];
#pragma unroll
    for (int i = 0; i < 4; i++)
#pragma unroll
        for (int j = 0; j < 8; j++) acc[i][j] = 0.f;

    for (int kc = 0; kc < D; kc += KC) {
        __syncthreads();
        // stage w chunk rows [kc, kc+32)
        for (int i = tid; i < KC * D; i += 256) {
            int k = i >> 7;
            int c = i & 127;
            ws[k * WS_STRIDE + c] = w[(long)(kc + k) * D + c];
        }
        __syncthreads();
#pragma unroll
        for (int kk = 0; kk < KC; kk++) {
            int k = kc + kk;
            float xv[4], wv[8];
#pragma unroll
            for (int i = 0; i < 4; i++) xv[i] = xs[(ty * 4 + i) * XS_STRIDE + k];
#pragma unroll
            for (int j = 0; j < 8; j++) wv[j] = ws[kk * WS_STRIDE + tx + 16 * j];
#pragma unroll
            for (int i = 0; i < 4; i++)
#pragma unroll
                for (int j = 0; j < 8; j++) acc[i][j] += xv[i] * wv[j];
        }
    }

#pragma unroll
    for (int i = 0; i < 4; i++) {
        int r = row0 + ty * 4 + i;
        if (r < nrows) {
#pragma unroll
            for (int j = 0; j < 8; j++)
                h[(long)r * D + tx + 16 * j] = acc[i][j];
        }
    }
}

// ---------------- init out[n][c] = b[c] (harness poisons d_out each call) ----
__global__ __launch_bounds__(256) void init_out(float* __restrict__ out,
                                                const float* __restrict__ b) {
    int i = blockIdx.x * 256 + threadIdx.x;      // float4 index, 32 per row
    if (i >= NODES * (D / 4)) return;
    int c4 = (i & 31) * 4;
    float4 bv = *(const float4*)(b + c4);
    ((float4*)out)[i] = bv;
}

// ---------------- edge scatter: out[dst] += val * h[src] --------------------
// 32 threads per edge, float4 per thread. unsafeAtomicAdd -> HW
// global_atomic_add_f32 (no CAS loop; denorm-flush semantics irrelevant here).
__global__ __launch_bounds__(256) void scatter_edges(const int* __restrict__ esrc,
                                                     const int* __restrict__ edst,
                                                     const float* __restrict__ eval,
                                                     const float* __restrict__ h,
                                                     float* __restrict__ out) {
    long gid = (long)blockIdx.x * 256 + threadIdx.x;
    int e = (int)(gid >> 5);
    if (e >= EDGES) return;
    int q = ((int)gid & 31) << 2;   // col offset 0,4,...,124
    int src = esrc[e];
    int dst = edst[e];
    float v = eval[e];
    float4 hv = *(const float4*)(h + (long)src * D + q);
    float* o = out + (long)dst * D + q;
    unsafeAtomicAdd(o + 0, v * hv.x);
    unsafeAtomicAdd(o + 1, v * hv.y);
    unsafeAtomicAdd(o + 2, v * hv.z);
    unsafeAtomicAdd(o + 3, v * hv.w);
}

// ---------------- epilogue: out = max(out, 0)  (bias already in init) -------
__global__ __launch_bounds__(256) void relu_inplace(float* __restrict__ out) {
    int i = blockIdx.x * 256 + threadIdx.x;
    if (i >= NODES * (D / 4)) return;
    float4 v = ((float4*)out)[i];
    v.x = fmaxf(v.x, 0.f);
    v.y = fmaxf(v.y, 0.f);
    v.z = fmaxf(v.z, 0.f);
    v.w = fmaxf(v.w, 0.f);
    ((float4*)out)[i] = v;
}

extern "C" void kernel_launch(void* const* d_in, const int* in_sizes, int n_in,
                              void* d_out, int out_size, void* d_ws, size_t ws_size,
                              hipStream_t stream) {
    const float* x    = (const float*)d_in[0];
    const int*   esrc = (const int*)  d_in[1];
    const int*   edst = (const int*)  d_in[2];
    const float* eval = (const float*)d_in[3];
    const float* w    = (const float*)d_in[4];
    const float* b    = (const float*)d_in[5];
    float* out = (float*)d_out;
    float* h   = (float*)d_ws;            // 100000*128*4 = 51.2 MB scratch

    gemm_xw<<<(NODES + TM - 1) / TM, 256, 0, stream>>>(x, w, h, NODES);
    init_out<<<(NODES * (D / 4) + 255) / 256, 256, 0, stream>>>(out, b);
    scatter_edges<<<(int)(((long)EDGES * 32 + 255) / 256), 256, 0, stream>>>(
        esrc, edst, eval, h, out);
    relu_inplace<<<(NODES * (D / 4) + 255) / 256, 256, 0, stream>>>(out);
}

// Round 2
// 1011.086 us; speedup vs baseline: 5.5225x; 5.5225x over previous
//
#include <hip/hip_runtime.h>

#define NODES 100000
#define EDGES 3200000
#define D 128

// ---------------- GEMM: h = x @ w (fp32 vector ALU; no fp32 MFMA on CDNA4) ---
#define TM 64
#define XS_STRIDE 129
#define WS_STRIDE 129
#define KC 32

__global__ __launch_bounds__(256) void gemm_xw(const float* __restrict__ x,
                                               const float* __restrict__ w,
                                               float* __restrict__ h,
                                               int nrows) {
    __shared__ float xs[TM * XS_STRIDE];
    __shared__ float ws[KC * WS_STRIDE];
    const int tid = threadIdx.x;
    const int tx = tid & 15;
    const int ty = tid >> 4;
    const int row0 = blockIdx.x * TM;

    for (int i = tid; i < TM * D; i += 256) {
        int r = i >> 7;
        int c = i & 127;
        int gr = row0 + r;
        xs[r * XS_STRIDE + c] = (gr < nrows) ? x[(long)gr * D + c] : 0.f;
    }

    float acc[4][8];
#pragma unroll
    for (int i = 0; i < 4; i++)
#pragma unroll
        for (int j = 0; j < 8; j++) acc[i][j] = 0.f;

    for (int kc = 0; kc < D; kc += KC) {
        __syncthreads();
        for (int i = tid; i < KC * D; i += 256) {
            int k = i >> 7;
            int c = i & 127;
            ws[k * WS_STRIDE + c] = w[(long)(kc + k) * D + c];
        }
        __syncthreads();
#pragma unroll
        for (int kk = 0; kk < KC; kk++) {
            int k = kc + kk;
            float xv[4], wv[8];
#pragma unroll
            for (int i = 0; i < 4; i++) xv[i] = xs[(ty * 4 + i) * XS_STRIDE + k];
#pragma unroll
            for (int j = 0; j < 8; j++) wv[j] = ws[kk * WS_STRIDE + tx + 16 * j];
#pragma unroll
            for (int i = 0; i < 4; i++)
#pragma unroll
                for (int j = 0; j < 8; j++) acc[i][j] += xv[i] * wv[j];
        }
    }

#pragma unroll
    for (int i = 0; i < 4; i++) {
        int r = row0 + ty * 4 + i;
        if (r < nrows) {
#pragma unroll
            for (int j = 0; j < 8; j++)
                h[(long)r * D + tx + 16 * j] = acc[i][j];
        }
    }
}

// ---------------- counting sort by dst: zero -> histogram -> scan -> permute -

__global__ __launch_bounds__(256) void zero_counts(int* __restrict__ cnt, int n) {
    int i = blockIdx.x * 256 + threadIdx.x;
    if (i < n) cnt[i] = 0;
}

__global__ __launch_bounds__(256) void histogram_dst(const int* __restrict__ edst,
                                                     int* __restrict__ cnt) {
    int e = blockIdx.x * 256 + threadIdx.x;
    if (e < EDGES) atomicAdd(&cnt[edst[e]], 1);
}

// single 1024-thread block; in-place exclusive scan of cnt[0..NODES-1] into
// row_ptr (same array, NODES+1 entries); also initializes cursor = row_ptr.
__global__ __launch_bounds__(1024) void scan_counts(int* __restrict__ rp,
                                                    int* __restrict__ cursor) {
    __shared__ int sdata[1024];
    const int tid = threadIdx.x;
    const int chunk = (NODES + 1023) / 1024;      // 98
    const int beg = tid * chunk;
    const int end = min(beg + chunk, NODES);

    int partial = 0;
    for (int i = beg; i < end; i++) partial += rp[i];
    sdata[tid] = partial;
    __syncthreads();
    // inclusive Hillis-Steele
    for (int off = 1; off < 1024; off <<= 1) {
        int v = (tid >= off) ? sdata[tid - off] : 0;
        __syncthreads();
        sdata[tid] += v;
        __syncthreads();
    }
    int running = (tid > 0) ? sdata[tid - 1] : 0;  // exclusive base
    for (int i = beg; i < end; i++) {
        int c = rp[i];
        rp[i] = running;
        cursor[i] = running;
        running += c;
    }
    if (tid == 1023) rp[NODES] = EDGES;
}

__global__ __launch_bounds__(256) void permute_edges(const int* __restrict__ esrc,
                                                     const int* __restrict__ edst,
                                                     const float* __restrict__ eval,
                                                     int* __restrict__ cursor,
                                                     int* __restrict__ ssrc,
                                                     float* __restrict__ sval) {
    int e = blockIdx.x * 256 + threadIdx.x;
    if (e >= EDGES) return;
    int dst = edst[e];
    int pos = atomicAdd(&cursor[dst], 1);
    ssrc[pos] = esrc[e];
    sval[pos] = eval[e];
}

// ---------------- atomic-free aggregation: 1 wave per node ------------------
// lane owns cols {2*lane, 2*lane+1}; per edge the wave reads 512 B of h[src]
// coalesced; accumulate in regs; fused bias+relu; out written exactly once.
__global__ __launch_bounds__(256) void aggregate(const int* __restrict__ rp,
                                                 const int* __restrict__ ssrc,
                                                 const float* __restrict__ sval,
                                                 const float* __restrict__ h,
                                                 const float* __restrict__ b,
                                                 float* __restrict__ out) {
    int node = blockIdx.x * 4 + (threadIdx.x >> 6);
    if (node >= NODES) return;
    int lane = threadIdx.x & 63;
    int beg = rp[node];
    int end = rp[node + 1];
    const float2* h2 = (const float2*)h;

    float2 acc = make_float2(0.f, 0.f);
    int e = beg;
    for (; e + 1 < end; e += 2) {      // 2-edge unroll for load ILP
        int s0 = ssrc[e];
        int s1 = ssrc[e + 1];
        float v0 = sval[e];
        float v1 = sval[e + 1];
        float2 h0 = h2[(long)s0 * 64 + lane];
        float2 h1 = h2[(long)s1 * 64 + lane];
        acc.x += v0 * h0.x + v1 * h1.x;
        acc.y += v0 * h0.y + v1 * h1.y;
    }
    if (e < end) {
        int s0 = ssrc[e];
        float v0 = sval[e];
        float2 h0 = h2[(long)s0 * 64 + lane];
        acc.x += v0 * h0.x;
        acc.y += v0 * h0.y;
    }
    float2 bv = ((const float2*)b)[lane];
    acc.x = fmaxf(acc.x + bv.x, 0.f);
    acc.y = fmaxf(acc.y + bv.y, 0.f);
    ((float2*)out)[(long)node * 64 + lane] = acc;
}

// ---------------- fallback path (round-1 atomic scatter) --------------------
__global__ __launch_bounds__(256) void init_out(float* __restrict__ out,
                                                const float* __restrict__ b) {
    int i = blockIdx.x * 256 + threadIdx.x;
    if (i >= NODES * (D / 4)) return;
    int c4 = (i & 31) * 4;
    float4 bv = *(const float4*)(b + c4);
    ((float4*)out)[i] = bv;
}

__global__ __launch_bounds__(256) void scatter_edges(const int* __restrict__ esrc,
                                                     const int* __restrict__ edst,
                                                     const float* __restrict__ eval,
                                                     const float* __restrict__ h,
                                                     float* __restrict__ out) {
    long gid = (long)blockIdx.x * 256 + threadIdx.x;
    int e = (int)(gid >> 5);
    if (e >= EDGES) return;
    int q = ((int)gid & 31) << 2;
    int src = esrc[e];
    int dst = edst[e];
    float v = eval[e];
    float4 hv = *(const float4*)(h + (long)src * D + q);
    float* o = out + (long)dst * D + q;
    unsafeAtomicAdd(o + 0, v * hv.x);
    unsafeAtomicAdd(o + 1, v * hv.y);
    unsafeAtomicAdd(o + 2, v * hv.z);
    unsafeAtomicAdd(o + 3, v * hv.w);
}

__global__ __launch_bounds__(256) void relu_inplace(float* __restrict__ out) {
    int i = blockIdx.x * 256 + threadIdx.x;
    if (i >= NODES * (D / 4)) return;
    float4 v = ((float4*)out)[i];
    v.x = fmaxf(v.x, 0.f);
    v.y = fmaxf(v.y, 0.f);
    v.z = fmaxf(v.z, 0.f);
    v.w = fmaxf(v.w, 0.f);
    ((float4*)out)[i] = v;
}

extern "C" void kernel_launch(void* const* d_in, const int* in_sizes, int n_in,
                              void* d_out, int out_size, void* d_ws, size_t ws_size,
                              hipStream_t stream) {
    const float* x    = (const float*)d_in[0];
    const int*   esrc = (const int*)  d_in[1];
    const int*   edst = (const int*)  d_in[2];
    const float* eval = (const float*)d_in[3];
    const float* w    = (const float*)d_in[4];
    const float* b    = (const float*)d_in[5];
    float* out = (float*)d_out;

    // workspace layout (bytes)
    char* ws = (char*)d_ws;
    const size_t OFF_H      = 0;                           // 51,200,000
    const size_t OFF_RP     = 51200000;                    // (NODES+1)*4 -> pad 400,064
    const size_t OFF_CUR    = OFF_RP  + 400064;            // 400,000
    const size_t OFF_SSRC   = OFF_CUR + 400000;            // 12,800,000
    const size_t OFF_SVAL   = OFF_SSRC + 12800000;         // 12,800,000
    const size_t REQUIRED   = OFF_SVAL + 12800000;         // ~77.6 MB

    float* h = (float*)(ws + OFF_H);

    gemm_xw<<<(NODES + TM - 1) / TM, 256, 0, stream>>>(x, w, h, NODES);

    if (ws_size >= REQUIRED) {
        int*   rp     = (int*)  (ws + OFF_RP);
        int*   cursor = (int*)  (ws + OFF_CUR);
        int*   ssrc   = (int*)  (ws + OFF_SSRC);
        float* sval   = (float*)(ws + OFF_SVAL);

        zero_counts<<<(NODES + 1 + 255) / 256, 256, 0, stream>>>(rp, NODES + 1);
        histogram_dst<<<(EDGES + 255) / 256, 256, 0, stream>>>(edst, rp);
        scan_counts<<<1, 1024, 0, stream>>>(rp, cursor);
        permute_edges<<<(EDGES + 255) / 256, 256, 0, stream>>>(
            esrc, edst, eval, cursor, ssrc, sval);
        aggregate<<<(NODES + 3) / 4, 256, 0, stream>>>(rp, ssrc, sval, h, b, out);
    } else {
        // fallback: atomic scatter (round-1 path)
        init_out<<<(NODES * (D / 4) + 255) / 256, 256, 0, stream>>>(out, b);
        scatter_edges<<<(int)(((long)EDGES * 32 + 255) / 256), 256, 0, stream>>>(
            esrc, edst, eval, h, out);
        relu_inplace<<<(NODES * (D / 4) + 255) / 256, 256, 0, stream>>>(out);
    }
}

// Round 3
// 826.120 us; speedup vs baseline: 6.7589x; 1.2239x over previous
//
#include <hip/hip_runtime.h>

#define NODES 100000
#define EDGES 3200000
#define D 128
#define NB_SCAN ((NODES + 255) / 256)   // 391 scan blocks

// ---------------- GEMM: h = x @ w (fp32 vector ALU; no fp32 MFMA on CDNA4) ---
#define TM 64
#define XS_STRIDE 129
#define WS_STRIDE 129
#define KC 32

__global__ __launch_bounds__(256) void gemm_xw(const float* __restrict__ x,
                                               const float* __restrict__ w,
                                               float* __restrict__ h,
                                               int nrows) {
    __shared__ float xs[TM * XS_STRIDE];
    __shared__ float ws[KC * WS_STRIDE];
    const int tid = threadIdx.x;
    const int tx = tid & 15;
    const int ty = tid >> 4;
    const int row0 = blockIdx.x * TM;

    for (int i = tid; i < TM * D; i += 256) {
        int r = i >> 7;
        int c = i & 127;
        int gr = row0 + r;
        xs[r * XS_STRIDE + c] = (gr < nrows) ? x[(long)gr * D + c] : 0.f;
    }

    float acc[4][8];
#pragma unroll
    for (int i = 0; i < 4; i++)
#pragma unroll
        for (int j = 0; j < 8; j++) acc[i][j] = 0.f;

    for (int kc = 0; kc < D; kc += KC) {
        __syncthreads();
        for (int i = tid; i < KC * D; i += 256) {
            int k = i >> 7;
            int c = i & 127;
            ws[k * WS_STRIDE + c] = w[(long)(kc + k) * D + c];
        }
        __syncthreads();
#pragma unroll
        for (int kk = 0; kk < KC; kk++) {
            int k = kc + kk;
            float xv[4], wv[8];
#pragma unroll
            for (int i = 0; i < 4; i++) xv[i] = xs[(ty * 4 + i) * XS_STRIDE + k];
#pragma unroll
            for (int j = 0; j < 8; j++) wv[j] = ws[kk * WS_STRIDE + tx + 16 * j];
#pragma unroll
            for (int i = 0; i < 4; i++)
#pragma unroll
                for (int j = 0; j < 8; j++) acc[i][j] += xv[i] * wv[j];
        }
    }

#pragma unroll
    for (int i = 0; i < 4; i++) {
        int r = row0 + ty * 4 + i;
        if (r < nrows) {
#pragma unroll
            for (int j = 0; j < 8; j++)
                h[(long)r * D + tx + 16 * j] = acc[i][j];
        }
    }
}

// ---------------- counting sort by dst ---------------------------------------

__global__ __launch_bounds__(256) void zero_counts(int* __restrict__ cnt, int n) {
    int i = blockIdx.x * 256 + threadIdx.x;
    if (i < n) cnt[i] = 0;
}

__global__ __launch_bounds__(256) void histogram_dst(const int* __restrict__ edst,
                                                     int* __restrict__ cnt) {
    int e = blockIdx.x * 256 + threadIdx.x;
    if (e < EDGES) atomicAdd(&cnt[edst[e]], 1);
}

// device-wide exclusive scan, 3 kernels (391 blocks x 256):
// k1: per-block sum -> partials[b]
__global__ __launch_bounds__(256) void scan_k1(const int* __restrict__ cnt,
                                               int* __restrict__ partials) {
    int tid = threadIdx.x;
    int i = blockIdx.x * 256 + tid;
    int v = (i < NODES) ? cnt[i] : 0;
#pragma unroll
    for (int off = 32; off > 0; off >>= 1) v += __shfl_down(v, off, 64);
    __shared__ int wsum[4];
    int lane = tid & 63, wid = tid >> 6;
    if (lane == 0) wsum[wid] = v;
    __syncthreads();
    if (tid == 0) partials[blockIdx.x] = wsum[0] + wsum[1] + wsum[2] + wsum[3];
}

// k2: single small block scans the 391 partials in-place (exclusive)
__global__ __launch_bounds__(512) void scan_k2(int* __restrict__ partials) {
    __shared__ int sd[512];
    int tid = threadIdx.x;
    sd[tid] = (tid < NB_SCAN) ? partials[tid] : 0;
    __syncthreads();
#pragma unroll
    for (int off = 1; off < 512; off <<= 1) {
        int t = (tid >= off) ? sd[tid - off] : 0;
        __syncthreads();
        sd[tid] += t;
        __syncthreads();
    }
    if (tid < NB_SCAN) partials[tid] = (tid > 0) ? sd[tid - 1] : 0;
}

// k3: block-local exclusive scan + partial offset -> rp, cursor (in-place ok:
// each block reads/writes only its own disjoint range)
__global__ __launch_bounds__(256) void scan_k3(int* __restrict__ rp,
                                               int* __restrict__ cursor,
                                               const int* __restrict__ partials) {
    int tid = threadIdx.x;
    int i = blockIdx.x * 256 + tid;
    int v = (i < NODES) ? rp[i] : 0;
    int lane = tid & 63, wid = tid >> 6;
    int s = v;
#pragma unroll
    for (int off = 1; off < 64; off <<= 1) {
        int t = __shfl_up(s, off, 64);
        if (lane >= off) s += t;
    }
    __shared__ int wsum[4];
    if (lane == 63) wsum[wid] = s;
    __syncthreads();
    int base = partials[blockIdx.x];
    for (int w = 0; w < wid; w++) base += wsum[w];
    int excl = base + s - v;
    if (i < NODES) {
        rp[i] = excl;
        cursor[i] = excl;
    }
    if (i == 0) rp[NODES] = EDGES;
}

// permute: single packed int2 {src, val_bits} scattered 8B store per edge
__global__ __launch_bounds__(256) void permute_edges(const int* __restrict__ esrc,
                                                     const int* __restrict__ edst,
                                                     const float* __restrict__ eval,
                                                     int* __restrict__ cursor,
                                                     int2* __restrict__ spack) {
    int e = blockIdx.x * 256 + threadIdx.x;
    if (e >= EDGES) return;
    int dst = edst[e];
    int pos = atomicAdd(&cursor[dst], 1);
    spack[pos] = make_int2(esrc[e], __float_as_int(eval[e]));
}

// ---------------- atomic-free aggregation: 2 nodes per wave, float4/lane -----
// half-wave (32 lanes) owns one node; lane owns cols 4*l..4*l+3. Per edge one
// dwordx4 load per lane -> one vmem instr covers 2 edges (one per half-wave).
__global__ __launch_bounds__(256) void aggregate(const int* __restrict__ rp,
                                                 const int2* __restrict__ spack,
                                                 const float* __restrict__ h,
                                                 const float* __restrict__ b,
                                                 float* __restrict__ out) {
    int tid = threadIdx.x;
    int node = blockIdx.x * 8 + (tid >> 5);
    if (node >= NODES) return;
    int l = tid & 31;
    int beg = rp[node];
    int end = rp[node + 1];
    const float4* h4 = (const float4*)h;   // row stride = 32 float4

    float4 acc = make_float4(0.f, 0.f, 0.f, 0.f);
    int e = beg;
    for (; e + 3 < end; e += 4) {          // 4-edge unroll: 4 outstanding dwordx4
        int2 p0 = spack[e];
        int2 p1 = spack[e + 1];
        int2 p2 = spack[e + 2];
        int2 p3 = spack[e + 3];
        float4 a0 = h4[(long)p0.x * 32 + l];
        float4 a1 = h4[(long)p1.x * 32 + l];
        float4 a2 = h4[(long)p2.x * 32 + l];
        float4 a3 = h4[(long)p3.x * 32 + l];
        float v0 = __int_as_float(p0.y), v1 = __int_as_float(p1.y);
        float v2 = __int_as_float(p2.y), v3 = __int_as_float(p3.y);
        acc.x += v0 * a0.x + v1 * a1.x + v2 * a2.x + v3 * a3.x;
        acc.y += v0 * a0.y + v1 * a1.y + v2 * a2.y + v3 * a3.y;
        acc.z += v0 * a0.z + v1 * a1.z + v2 * a2.z + v3 * a3.z;
        acc.w += v0 * a0.w + v1 * a1.w + v2 * a2.w + v3 * a3.w;
    }
    for (; e < end; e++) {
        int2 p = spack[e];
        float v = __int_as_float(p.y);
        float4 a = h4[(long)p.x * 32 + l];
        acc.x += v * a.x;
        acc.y += v * a.y;
        acc.z += v * a.z;
        acc.w += v * a.w;
    }
    float4 bv = ((const float4*)b)[l];
    acc.x = fmaxf(acc.x + bv.x, 0.f);
    acc.y = fmaxf(acc.y + bv.y, 0.f);
    acc.z = fmaxf(acc.z + bv.z, 0.f);
    acc.w = fmaxf(acc.w + bv.w, 0.f);
    ((float4*)out)[(long)node * 32 + l] = acc;
}

// ---------------- fallback path (round-1 atomic scatter) --------------------
__global__ __launch_bounds__(256) void init_out(float* __restrict__ out,
                                                const float* __restrict__ b) {
    int i = blockIdx.x * 256 + threadIdx.x;
    if (i >= NODES * (D / 4)) return;
    int c4 = (i & 31) * 4;
    float4 bv = *(const float4*)(b + c4);
    ((float4*)out)[i] = bv;
}

__global__ __launch_bounds__(256) void scatter_edges(const int* __restrict__ esrc,
                                                     const int* __restrict__ edst,
                                                     const float* __restrict__ eval,
                                                     const float* __restrict__ h,
                                                     float* __restrict__ out) {
    long gid = (long)blockIdx.x * 256 + threadIdx.x;
    int e = (int)(gid >> 5);
    if (e >= EDGES) return;
    int q = ((int)gid & 31) << 2;
    int src = esrc[e];
    int dst = edst[e];
    float v = eval[e];
    float4 hv = *(const float4*)(h + (long)src * D + q);
    float* o = out + (long)dst * D + q;
    unsafeAtomicAdd(o + 0, v * hv.x);
    unsafeAtomicAdd(o + 1, v * hv.y);
    unsafeAtomicAdd(o + 2, v * hv.z);
    unsafeAtomicAdd(o + 3, v * hv.w);
}

__global__ __launch_bounds__(256) void relu_inplace(float* __restrict__ out) {
    int i = blockIdx.x * 256 + threadIdx.x;
    if (i >= NODES * (D / 4)) return;
    float4 v = ((float4*)out)[i];
    v.x = fmaxf(v.x, 0.f);
    v.y = fmaxf(v.y, 0.f);
    v.z = fmaxf(v.z, 0.f);
    v.w = fmaxf(v.w, 0.f);
    ((float4*)out)[i] = v;
}

extern "C" void kernel_launch(void* const* d_in, const int* in_sizes, int n_in,
                              void* d_out, int out_size, void* d_ws, size_t ws_size,
                              hipStream_t stream) {
    const float* x    = (const float*)d_in[0];
    const int*   esrc = (const int*)  d_in[1];
    const int*   edst = (const int*)  d_in[2];
    const float* eval = (const float*)d_in[3];
    const float* w    = (const float*)d_in[4];
    const float* b    = (const float*)d_in[5];
    float* out = (float*)d_out;

    // workspace layout (bytes)
    char* ws = (char*)d_ws;
    const size_t OFF_H     = 0;                            // 51,200,000
    const size_t OFF_RP    = 51200000;                     // (NODES+1)*4 pad->400,064
    const size_t OFF_CUR   = OFF_RP  + 400064;             // 400,064
    const size_t OFF_PART  = OFF_CUR + 400064;             // 391*4 pad->2048
    const size_t OFF_PACK  = OFF_PART + 2048;              // 25,600,000 (int2)
    const size_t REQUIRED  = OFF_PACK + 25600000;          // ~77.6 MB

    float* h = (float*)(ws + OFF_H);

    gemm_xw<<<(NODES + TM - 1) / TM, 256, 0, stream>>>(x, w, h, NODES);

    if (ws_size >= REQUIRED) {
        int*  rp       = (int*) (ws + OFF_RP);
        int*  cursor   = (int*) (ws + OFF_CUR);
        int*  partials = (int*) (ws + OFF_PART);
        int2* spack    = (int2*)(ws + OFF_PACK);

        zero_counts<<<(NODES + 1 + 255) / 256, 256, 0, stream>>>(rp, NODES + 1);
        histogram_dst<<<(EDGES + 255) / 256, 256, 0, stream>>>(edst, rp);
        scan_k1<<<NB_SCAN, 256, 0, stream>>>(rp, partials);
        scan_k2<<<1, 512, 0, stream>>>(partials);
        scan_k3<<<NB_SCAN, 256, 0, stream>>>(rp, cursor, partials);
        permute_edges<<<(EDGES + 255) / 256, 256, 0, stream>>>(
            esrc, edst, eval, cursor, spack);
        aggregate<<<(NODES + 7) / 8, 256, 0, stream>>>(rp, spack, h, b, out);
    } else {
        init_out<<<(NODES * (D / 4) + 255) / 256, 256, 0, stream>>>(out, b);
        scatter_edges<<<(int)(((long)EDGES * 32 + 255) / 256), 256, 0, stream>>>(
            esrc, edst, eval, h, out);
        relu_inplace<<<(NODES * (D / 4) + 255) / 256, 256, 0, stream>>>(out);
    }
}

// Round 4
// 641.525 us; speedup vs baseline: 8.7038x; 1.2877x over previous
//
#include <hip/hip_runtime.h>

#define NODES 100000
#define EDGES 3200000
#define D 128
#define NB_SCAN ((NODES + 255) / 256)   // 391 scan blocks

typedef unsigned short us8 __attribute__((ext_vector_type(8)));

__device__ __forceinline__ unsigned short f32_to_bf16_rn(float f) {
    unsigned u = __float_as_uint(f);
    unsigned r = (u + 0x7FFFu + ((u >> 16) & 1u)) >> 16;   // RNE; no NaN inputs here
    return (unsigned short)r;
}

// ---------------- GEMM: h = x @ w, h stored bf16 (fp32 vector ALU) ----------
#define TM 64
#define XS_STRIDE 129
#define WS_STRIDE 129
#define KC 32

__global__ __launch_bounds__(256) void gemm_xw(const float* __restrict__ x,
                                               const float* __restrict__ w,
                                               unsigned short* __restrict__ hb,
                                               int nrows) {
    __shared__ float xs[TM * XS_STRIDE];
    __shared__ float ws[KC * WS_STRIDE];
    const int tid = threadIdx.x;
    const int tx = tid & 15;
    const int ty = tid >> 4;
    const int row0 = blockIdx.x * TM;

    for (int i = tid; i < TM * D; i += 256) {
        int r = i >> 7;
        int c = i & 127;
        int gr = row0 + r;
        xs[r * XS_STRIDE + c] = (gr < nrows) ? x[(long)gr * D + c] : 0.f;
    }

    float acc[4][8];
#pragma unroll
    for (int i = 0; i < 4; i++)
#pragma unroll
        for (int j = 0; j < 8; j++) acc[i][j] = 0.f;

    for (int kc = 0; kc < D; kc += KC) {
        __syncthreads();
        for (int i = tid; i < KC * D; i += 256) {
            int k = i >> 7;
            int c = i & 127;
            ws[k * WS_STRIDE + c] = w[(long)(kc + k) * D + c];
        }
        __syncthreads();
#pragma unroll
        for (int kk = 0; kk < KC; kk++) {
            int k = kc + kk;
            float xv[4], wv[8];
#pragma unroll
            for (int i = 0; i < 4; i++) xv[i] = xs[(ty * 4 + i) * XS_STRIDE + k];
#pragma unroll
            for (int j = 0; j < 8; j++) wv[j] = ws[kk * WS_STRIDE + tx + 16 * j];
#pragma unroll
            for (int i = 0; i < 4; i++)
#pragma unroll
                for (int j = 0; j < 8; j++) acc[i][j] += xv[i] * wv[j];
        }
    }

#pragma unroll
    for (int i = 0; i < 4; i++) {
        int r = row0 + ty * 4 + i;
        if (r < nrows) {
#pragma unroll
            for (int j = 0; j < 8; j++)
                hb[(long)r * D + tx + 16 * j] = f32_to_bf16_rn(acc[i][j]);
        }
    }
}

// ---------------- counting sort by dst ---------------------------------------

__global__ __launch_bounds__(256) void zero_counts(int* __restrict__ cnt, int n) {
    int i = blockIdx.x * 256 + threadIdx.x;
    if (i < n) cnt[i] = 0;
}

__global__ __launch_bounds__(256) void histogram_dst(const int* __restrict__ edst,
                                                     int* __restrict__ cnt) {
    int e = blockIdx.x * 256 + threadIdx.x;
    if (e < EDGES) atomicAdd(&cnt[edst[e]], 1);
}

__global__ __launch_bounds__(256) void scan_k1(const int* __restrict__ cnt,
                                               int* __restrict__ partials) {
    int tid = threadIdx.x;
    int i = blockIdx.x * 256 + tid;
    int v = (i < NODES) ? cnt[i] : 0;
#pragma unroll
    for (int off = 32; off > 0; off >>= 1) v += __shfl_down(v, off, 64);
    __shared__ int wsum[4];
    int lane = tid & 63, wid = tid >> 6;
    if (lane == 0) wsum[wid] = v;
    __syncthreads();
    if (tid == 0) partials[blockIdx.x] = wsum[0] + wsum[1] + wsum[2] + wsum[3];
}

__global__ __launch_bounds__(512) void scan_k2(int* __restrict__ partials) {
    __shared__ int sd[512];
    int tid = threadIdx.x;
    sd[tid] = (tid < NB_SCAN) ? partials[tid] : 0;
    __syncthreads();
#pragma unroll
    for (int off = 1; off < 512; off <<= 1) {
        int t = (tid >= off) ? sd[tid - off] : 0;
        __syncthreads();
        sd[tid] += t;
        __syncthreads();
    }
    if (tid < NB_SCAN) partials[tid] = (tid > 0) ? sd[tid - 1] : 0;
}

__global__ __launch_bounds__(256) void scan_k3(int* __restrict__ rp,
                                               int* __restrict__ cursor,
                                               const int* __restrict__ partials) {
    int tid = threadIdx.x;
    int i = blockIdx.x * 256 + tid;
    int v = (i < NODES) ? rp[i] : 0;
    int lane = tid & 63, wid = tid >> 6;
    int s = v;
#pragma unroll
    for (int off = 1; off < 64; off <<= 1) {
        int t = __shfl_up(s, off, 64);
        if (lane >= off) s += t;
    }
    __shared__ int wsum[4];
    if (lane == 63) wsum[wid] = s;
    __syncthreads();
    int base = partials[blockIdx.x];
    for (int w = 0; w < wid; w++) base += wsum[w];
    int excl = base + s - v;
    if (i < NODES) {
        rp[i] = excl;
        cursor[i] = excl;
    }
    if (i == 0) rp[NODES] = EDGES;
}

// permute: ONE packed 4B word per edge: [val_q15 << 17 | src_17b]
// val quantized to 15-bit fixed point (err <= 2^-15, ~1e-3 on out — negligible)
__global__ __launch_bounds__(256) void permute_edges(const int* __restrict__ esrc,
                                                     const int* __restrict__ edst,
                                                     const float* __restrict__ eval,
                                                     int* __restrict__ cursor,
                                                     unsigned int* __restrict__ epack) {
    int e = blockIdx.x * 256 + threadIdx.x;
    if (e >= EDGES) return;
    int dst = edst[e];
    unsigned q = (unsigned)(eval[e] * 32768.0f);
    if (q > 32767u) q = 32767u;
    unsigned pk = (q << 17) | (unsigned)esrc[e];
    int pos = atomicAdd(&cursor[dst], 1);
    epack[pos] = pk;
}

// ---------------- aggregation: 2 nodes/wave, bf16 h, edge-pairs -------------
// node per 32-lane half-wave; sub = lane bit 4 selects which edge of a pair;
// li = lane&15 owns cols 8*li..8*li+7. One dwordx4 (16B bf16x8) per lane
// covers TWO edges' rows per iteration; sub-halves combined via shfl_xor(16).
__global__ __launch_bounds__(256) void aggregate(const int* __restrict__ rp,
                                                 const unsigned int* __restrict__ epack,
                                                 const unsigned short* __restrict__ hb,
                                                 const float* __restrict__ b,
                                                 float* __restrict__ out) {
    int tid = threadIdx.x;
    int node = blockIdx.x * 8 + (tid >> 5);
    if (node >= NODES) return;
    int l = tid & 31;
    int sub = l >> 4;
    int li = l & 15;
    int beg = rp[node];
    int end = rp[node + 1];

    float acc[8];
#pragma unroll
    for (int k = 0; k < 8; k++) acc[k] = 0.f;

    int e = beg;
    for (; e + 3 < end; e += 4) {          // 2 pairs in flight
        unsigned p0 = epack[e + sub];
        unsigned p1 = epack[e + 2 + sub];
        int s0 = p0 & 0x1FFFF;
        int s1 = p1 & 0x1FFFF;
        float v0 = (float)(p0 >> 17) * (1.f / 32768.f);
        float v1 = (float)(p1 >> 17) * (1.f / 32768.f);
        us8 r0 = *(const us8*)(hb + (long)s0 * D + li * 8);
        us8 r1 = *(const us8*)(hb + (long)s1 * D + li * 8);
#pragma unroll
        for (int k = 0; k < 8; k++) {
            float f0 = __uint_as_float(((unsigned)r0[k]) << 16);
            float f1 = __uint_as_float(((unsigned)r1[k]) << 16);
            acc[k] += v0 * f0 + v1 * f1;
        }
    }
    for (; e + 1 < end; e += 2) {          // single pair
        unsigned p0 = epack[e + sub];
        int s0 = p0 & 0x1FFFF;
        float v0 = (float)(p0 >> 17) * (1.f / 32768.f);
        us8 r0 = *(const us8*)(hb + (long)s0 * D + li * 8);
#pragma unroll
        for (int k = 0; k < 8; k++)
            acc[k] += v0 * __uint_as_float(((unsigned)r0[k]) << 16);
    }
    if (e < end) {                         // odd tail: both subs, half weight
        unsigned p0 = epack[e];
        int s0 = p0 & 0x1FFFF;
        float v0 = (float)(p0 >> 17) * (0.5f / 32768.f);
        us8 r0 = *(const us8*)(hb + (long)s0 * D + li * 8);
#pragma unroll
        for (int k = 0; k < 8; k++)
            acc[k] += v0 * __uint_as_float(((unsigned)r0[k]) << 16);
    }

    // combine sub-halves (wave-lane ^ 16 stays within this node's 32 lanes)
#pragma unroll
    for (int k = 0; k < 8; k++) acc[k] += __shfl_xor(acc[k], 16, 64);

    int c0 = li * 8 + sub * 4;             // each lane writes 4 of its 8 cols
    float4 bv = *(const float4*)(b + c0);
    float4 o;
    o.x = fmaxf(acc[sub * 4 + 0] + bv.x, 0.f);
    o.y = fmaxf(acc[sub * 4 + 1] + bv.y, 0.f);
    o.z = fmaxf(acc[sub * 4 + 2] + bv.z, 0.f);
    o.w = fmaxf(acc[sub * 4 + 3] + bv.w, 0.f);
    *(float4*)(out + (long)node * D + c0) = o;
}

extern "C" void kernel_launch(void* const* d_in, const int* in_sizes, int n_in,
                              void* d_out, int out_size, void* d_ws, size_t ws_size,
                              hipStream_t stream) {
    const float* x    = (const float*)d_in[0];
    const int*   esrc = (const int*)  d_in[1];
    const int*   edst = (const int*)  d_in[2];
    const float* eval = (const float*)d_in[3];
    const float* w    = (const float*)d_in[4];
    const float* b    = (const float*)d_in[5];
    float* out = (float*)d_out;

    // workspace layout (bytes)
    char* ws = (char*)d_ws;
    const size_t OFF_H    = 0;                       // 25,600,000 (bf16 h)
    const size_t OFF_RP   = 25600000;                // 400,004 -> pad 400,064
    const size_t OFF_CUR  = OFF_RP  + 400064;
    const size_t OFF_PART = OFF_CUR + 400064;        // 2048
    const size_t OFF_EPK  = OFF_PART + 2048;         // 12,800,000
    // REQUIRED = ~39.2 MB (ws provided ~78 MB in prior rounds)

    unsigned short* hb     = (unsigned short*)(ws + OFF_H);
    int*            rp     = (int*)           (ws + OFF_RP);
    int*            cursor = (int*)           (ws + OFF_CUR);
    int*            parts  = (int*)           (ws + OFF_PART);
    unsigned int*   epack  = (unsigned int*)  (ws + OFF_EPK);

    gemm_xw<<<(NODES + TM - 1) / TM, 256, 0, stream>>>(x, w, hb, NODES);
    zero_counts<<<(NODES + 1 + 255) / 256, 256, 0, stream>>>(rp, NODES + 1);
    histogram_dst<<<(EDGES + 255) / 256, 256, 0, stream>>>(edst, rp);
    scan_k1<<<NB_SCAN, 256, 0, stream>>>(rp, parts);
    scan_k2<<<1, 512, 0, stream>>>(parts);
    scan_k3<<<NB_SCAN, 256, 0, stream>>>(rp, cursor, parts);
    permute_edges<<<(EDGES + 255) / 256, 256, 0, stream>>>(
        esrc, edst, eval, cursor, epack);
    aggregate<<<(NODES + 7) / 8, 256, 0, stream>>>(rp, epack, hb, b, out);
}

// Round 5
// 599.207 us; speedup vs baseline: 9.3185x; 1.0706x over previous
//
#include <hip/hip_runtime.h>

#define NODES 100000
#define EDGES 3200000
#define D 128
#define NB_SCAN ((NODES + 255) / 256)    // 391 scan blocks
#define NBUCKET ((NODES + 255) / 256)    // 391 dst-buckets of 256 nodes
#define CH 8192                           // edges per bin_pass1 block
#define NB_BIN ((EDGES + CH - 1) / CH)   // 391 binning blocks

typedef unsigned short us8 __attribute__((ext_vector_type(8)));

__device__ __forceinline__ unsigned short f32_to_bf16_rn(float f) {
    unsigned u = __float_as_uint(f);
    unsigned r = (u + 0x7FFFu + ((u >> 16) & 1u)) >> 16;   // RNE; no NaN inputs here
    return (unsigned short)r;
}

// ---------------- GEMM: h = x @ w, h stored bf16 (fp32 vector ALU) ----------
#define TM 64
#define XS_STRIDE 129
#define WS_STRIDE 129
#define KC 32

__global__ __launch_bounds__(256) void gemm_xw(const float* __restrict__ x,
                                               const float* __restrict__ w,
                                               unsigned short* __restrict__ hb,
                                               int nrows) {
    __shared__ float xs[TM * XS_STRIDE];
    __shared__ float ws[KC * WS_STRIDE];
    const int tid = threadIdx.x;
    const int tx = tid & 15;
    const int ty = tid >> 4;
    const int row0 = blockIdx.x * TM;

    for (int i = tid; i < TM * D; i += 256) {
        int r = i >> 7;
        int c = i & 127;
        int gr = row0 + r;
        xs[r * XS_STRIDE + c] = (gr < nrows) ? x[(long)gr * D + c] : 0.f;
    }

    float acc[4][8];
#pragma unroll
    for (int i = 0; i < 4; i++)
#pragma unroll
        for (int j = 0; j < 8; j++) acc[i][j] = 0.f;

    for (int kc = 0; kc < D; kc += KC) {
        __syncthreads();
        for (int i = tid; i < KC * D; i += 256) {
            int k = i >> 7;
            int c = i & 127;
            ws[k * WS_STRIDE + c] = w[(long)(kc + k) * D + c];
        }
        __syncthreads();
#pragma unroll
        for (int kk = 0; kk < KC; kk++) {
            int k = kc + kk;
            float xv[4], wv[8];
#pragma unroll
            for (int i = 0; i < 4; i++) xv[i] = xs[(ty * 4 + i) * XS_STRIDE + k];
#pragma unroll
            for (int j = 0; j < 8; j++) wv[j] = ws[kk * WS_STRIDE + tx + 16 * j];
#pragma unroll
            for (int i = 0; i < 4; i++)
#pragma unroll
                for (int j = 0; j < 8; j++) acc[i][j] += xv[i] * wv[j];
        }
    }

#pragma unroll
    for (int i = 0; i < 4; i++) {
        int r = row0 + ty * 4 + i;
        if (r < nrows) {
#pragma unroll
            for (int j = 0; j < 8; j++)
                hb[(long)r * D + tx + 16 * j] = f32_to_bf16_rn(acc[i][j]);
        }
    }
}

// ---------------- counting sort by dst: histogram + device-wide scan --------

__global__ __launch_bounds__(256) void zero_counts(int* __restrict__ cnt, int n) {
    int i = blockIdx.x * 256 + threadIdx.x;
    if (i < n) cnt[i] = 0;
}

__global__ __launch_bounds__(256) void histogram_dst(const int* __restrict__ edst,
                                                     int* __restrict__ cnt) {
    int e = blockIdx.x * 256 + threadIdx.x;
    if (e < EDGES) atomicAdd(&cnt[edst[e]], 1);
}

__global__ __launch_bounds__(256) void scan_k1(const int* __restrict__ cnt,
                                               int* __restrict__ partials) {
    int tid = threadIdx.x;
    int i = blockIdx.x * 256 + tid;
    int v = (i < NODES) ? cnt[i] : 0;
#pragma unroll
    for (int off = 32; off > 0; off >>= 1) v += __shfl_down(v, off, 64);
    __shared__ int wsum[4];
    int lane = tid & 63, wid = tid >> 6;
    if (lane == 0) wsum[wid] = v;
    __syncthreads();
    if (tid == 0) partials[blockIdx.x] = wsum[0] + wsum[1] + wsum[2] + wsum[3];
}

__global__ __launch_bounds__(512) void scan_k2(int* __restrict__ partials) {
    __shared__ int sd[512];
    int tid = threadIdx.x;
    sd[tid] = (tid < NB_SCAN) ? partials[tid] : 0;
    __syncthreads();
#pragma unroll
    for (int off = 1; off < 512; off <<= 1) {
        int t = (tid >= off) ? sd[tid - off] : 0;
        __syncthreads();
        sd[tid] += t;
        __syncthreads();
    }
    if (tid < NB_SCAN) partials[tid] = (tid > 0) ? sd[tid - 1] : 0;
}

// k3: also seeds per-node cursor and per-bucket cursor (bcur[b] = rp[b*256])
__global__ __launch_bounds__(256) void scan_k3(int* __restrict__ rp,
                                               int* __restrict__ cursor,
                                               int* __restrict__ bcur,
                                               const int* __restrict__ partials) {
    int tid = threadIdx.x;
    int i = blockIdx.x * 256 + tid;
    int v = (i < NODES) ? rp[i] : 0;
    int lane = tid & 63, wid = tid >> 6;
    int s = v;
#pragma unroll
    for (int off = 1; off < 64; off <<= 1) {
        int t = __shfl_up(s, off, 64);
        if (lane >= off) s += t;
    }
    __shared__ int wsum[4];
    if (lane == 63) wsum[wid] = s;
    __syncthreads();
    int base = partials[blockIdx.x];
    for (int w = 0; w < wid; w++) base += wsum[w];
    int excl = base + s - v;
    if (i < NODES) {
        rp[i] = excl;
        cursor[i] = excl;
        if ((i & 255) == 0) bcur[i >> 8] = excl;
    }
    if (i == 0) rp[NODES] = EDGES;
}

// ---------------- two-level binned permute ----------------------------------
// pass 1: bin edges by dst>>8 into CSR-coordinate bucket regions.
// Each block: LDS histogram over 391 buckets -> one global atomicAdd per
// (block,bucket) run reservation -> scattered int2 stores whose lines are
// block-local and L2-merge (writeback ~= payload, not 64B/edge).
__global__ __launch_bounds__(256) void bin_pass1(const int* __restrict__ esrc,
                                                 const int* __restrict__ edst,
                                                 const float* __restrict__ eval,
                                                 int* __restrict__ bcur,
                                                 int2* __restrict__ tmp) {
    __shared__ int hist[NBUCKET];
    __shared__ int base[NBUCKET];
    __shared__ int lcur[NBUCKET];
    const int tid = threadIdx.x;
    const long e0 = (long)blockIdx.x * CH;

    for (int b = tid; b < NBUCKET; b += 256) { hist[b] = 0; lcur[b] = 0; }
    __syncthreads();
    for (int i = tid; i < CH; i += 256) {
        long e = e0 + i;
        if (e < EDGES) atomicAdd(&hist[edst[e] >> 8], 1);
    }
    __syncthreads();
    for (int b = tid; b < NBUCKET; b += 256) {
        int c = hist[b];
        if (c > 0) base[b] = atomicAdd(&bcur[b], c);
    }
    __syncthreads();
    for (int i = tid; i < CH; i += 256) {
        long e = e0 + i;
        if (e < EDGES) {
            int dst = edst[e];
            unsigned q = (unsigned)(eval[e] * 32768.0f);
            if (q > 32767u) q = 32767u;
            unsigned pk = (q << 17) | (unsigned)esrc[e];
            int bk = dst >> 8;
            int pos = base[bk] + atomicAdd(&lcur[bk], 1);
            tmp[pos] = make_int2((int)pk, dst);
        }
    }
}

// pass 2: one block per bucket (keeps the ~32KB epack window + 1KB cursor
// window in a single XCD's L2). Sequential tmp read, L2-local scatter.
__global__ __launch_bounds__(256) void bin_pass2(const int* __restrict__ rp,
                                                 const int2* __restrict__ tmp,
                                                 int* __restrict__ cursor,
                                                 unsigned int* __restrict__ epack) {
    int b = blockIdx.x;
    int node0 = b << 8;
    int node1 = min(node0 + 256, NODES);
    int beg = rp[node0];
    int end = rp[node1];
    for (int i = beg + threadIdx.x; i < end; i += 256) {
        int2 t = tmp[i];
        int pos = atomicAdd(&cursor[t.y], 1);
        epack[pos] = (unsigned)t.x;
    }
}

// ---------------- aggregation: 2 nodes/wave, bf16 h, edge-pairs -------------
__global__ __launch_bounds__(256) void aggregate(const int* __restrict__ rp,
                                                 const unsigned int* __restrict__ epack,
                                                 const unsigned short* __restrict__ hb,
                                                 const float* __restrict__ b,
                                                 float* __restrict__ out) {
    int tid = threadIdx.x;
    int node = blockIdx.x * 8 + (tid >> 5);
    if (node >= NODES) return;
    int l = tid & 31;
    int sub = l >> 4;
    int li = l & 15;
    int beg = rp[node];
    int end = rp[node + 1];

    float acc[8];
#pragma unroll
    for (int k = 0; k < 8; k++) acc[k] = 0.f;

    int e = beg;
    for (; e + 3 < end; e += 4) {
        unsigned p0 = epack[e + sub];
        unsigned p1 = epack[e + 2 + sub];
        int s0 = p0 & 0x1FFFF;
        int s1 = p1 & 0x1FFFF;
        float v0 = (float)(p0 >> 17) * (1.f / 32768.f);
        float v1 = (float)(p1 >> 17) * (1.f / 32768.f);
        us8 r0 = *(const us8*)(hb + (long)s0 * D + li * 8);
        us8 r1 = *(const us8*)(hb + (long)s1 * D + li * 8);
#pragma unroll
        for (int k = 0; k < 8; k++) {
            float f0 = __uint_as_float(((unsigned)r0[k]) << 16);
            float f1 = __uint_as_float(((unsigned)r1[k]) << 16);
            acc[k] += v0 * f0 + v1 * f1;
        }
    }
    for (; e + 1 < end; e += 2) {
        unsigned p0 = epack[e + sub];
        int s0 = p0 & 0x1FFFF;
        float v0 = (float)(p0 >> 17) * (1.f / 32768.f);
        us8 r0 = *(const us8*)(hb + (long)s0 * D + li * 8);
#pragma unroll
        for (int k = 0; k < 8; k++)
            acc[k] += v0 * __uint_as_float(((unsigned)r0[k]) << 16);
    }
    if (e < end) {                         // odd tail: both subs, half weight
        unsigned p0 = epack[e];
        int s0 = p0 & 0x1FFFF;
        float v0 = (float)(p0 >> 17) * (0.5f / 32768.f);
        us8 r0 = *(const us8*)(hb + (long)s0 * D + li * 8);
#pragma unroll
        for (int k = 0; k < 8; k++)
            acc[k] += v0 * __uint_as_float(((unsigned)r0[k]) << 16);
    }

#pragma unroll
    for (int k = 0; k < 8; k++) acc[k] += __shfl_xor(acc[k], 16, 64);

    int c0 = li * 8 + sub * 4;
    float4 bv = *(const float4*)(b + c0);
    float4 o;
    o.x = fmaxf(acc[sub * 4 + 0] + bv.x, 0.f);
    o.y = fmaxf(acc[sub * 4 + 1] + bv.y, 0.f);
    o.z = fmaxf(acc[sub * 4 + 2] + bv.z, 0.f);
    o.w = fmaxf(acc[sub * 4 + 3] + bv.w, 0.f);
    *(float4*)(out + (long)node * D + c0) = o;
}

extern "C" void kernel_launch(void* const* d_in, const int* in_sizes, int n_in,
                              void* d_out, int out_size, void* d_ws, size_t ws_size,
                              hipStream_t stream) {
    const float* x    = (const float*)d_in[0];
    const int*   esrc = (const int*)  d_in[1];
    const int*   edst = (const int*)  d_in[2];
    const float* eval = (const float*)d_in[3];
    const float* w    = (const float*)d_in[4];
    const float* b    = (const float*)d_in[5];
    float* out = (float*)d_out;

    // workspace layout (bytes), total ~64.8 MB
    char* ws = (char*)d_ws;
    const size_t OFF_H    = 0;                       // 25,600,000 (bf16 h)
    const size_t OFF_RP   = 25600000;                // 400,004 -> pad 400,064
    const size_t OFF_CUR  = OFF_RP   + 400064;
    const size_t OFF_PART = OFF_CUR  + 400064;       // 2048
    const size_t OFF_BCUR = OFF_PART + 2048;         // 391*4 -> pad 2048
    const size_t OFF_TMP  = OFF_BCUR + 2048;         // 25,600,000 (int2)
    const size_t OFF_EPK  = OFF_TMP  + 25600000;     // 12,800,000

    unsigned short* hb     = (unsigned short*)(ws + OFF_H);
    int*            rp     = (int*)           (ws + OFF_RP);
    int*            cursor = (int*)           (ws + OFF_CUR);
    int*            parts  = (int*)           (ws + OFF_PART);
    int*            bcur   = (int*)           (ws + OFF_BCUR);
    int2*           tmp    = (int2*)          (ws + OFF_TMP);
    unsigned int*   epack  = (unsigned int*)  (ws + OFF_EPK);

    gemm_xw<<<(NODES + TM - 1) / TM, 256, 0, stream>>>(x, w, hb, NODES);
    zero_counts<<<(NODES + 1 + 255) / 256, 256, 0, stream>>>(rp, NODES + 1);
    histogram_dst<<<(EDGES + 255) / 256, 256, 0, stream>>>(edst, rp);
    scan_k1<<<NB_SCAN, 256, 0, stream>>>(rp, parts);
    scan_k2<<<1, 512, 0, stream>>>(parts);
    scan_k3<<<NB_SCAN, 256, 0, stream>>>(rp, cursor, bcur, parts);
    bin_pass1<<<NB_BIN, 256, 0, stream>>>(esrc, edst, eval, bcur, tmp);
    bin_pass2<<<NBUCKET, 256, 0, stream>>>(rp, tmp, cursor, epack);
    aggregate<<<(NODES + 7) / 8, 256, 0, stream>>>(rp, epack, hb, b, out);
}

// Round 6
// 368.326 us; speedup vs baseline: 15.1597x; 1.6268x over previous
//
#include <hip/hip_runtime.h>

#define NODES 100000
#define EDGES 3200000
#define D 128
#define NBUCKET ((NODES + 255) / 256)    // 391 dst-buckets of 256 nodes
#define CH 8192                          // edges per binning block
#define NB_BIN ((EDGES + CH - 1) / CH)   // 391 binning blocks

typedef unsigned short us8 __attribute__((ext_vector_type(8)));
typedef short bf16x8 __attribute__((ext_vector_type(8)));
typedef float f32x4 __attribute__((ext_vector_type(4)));

__device__ __forceinline__ unsigned short f32_to_bf16_rn(float f) {
    unsigned u = __float_as_uint(f);
    unsigned r = (u + 0x7FFFu + ((u >> 16) & 1u)) >> 16;   // RNE; no NaN inputs here
    return (unsigned short)r;
}

// ---------------- w prep: fp32 [128][128] -> bf16 in B-fragment order -------
// wt[((ct*4 + c)*64 + lane)*8 + j] = bf16(w[(32c + (lane>>4)*8 + j)][16ct + (lane&15)])
__global__ __launch_bounds__(256) void wprep(const float* __restrict__ w,
                                             unsigned short* __restrict__ wt) {
    int i = blockIdx.x * 256 + threadIdx.x;
    if (i >= 16384) return;
    int j  = i & 7;
    int l  = (i >> 3) & 63;
    int c  = (i >> 9) & 3;
    int ct = i >> 11;
    int k   = 32 * c + ((l >> 4) << 3) + j;
    int col = (ct << 4) + (l & 15);
    wt[i] = f32_to_bf16_rn(w[k * D + col]);
}

// ---------------- GEMM via MFMA: h = bf16(x) @ bf16(w), hb bf16 -------------
// One wave = 16 rows x 128 cols; 4 K-chunks x 8 col-tiles = 32 MFMAs.
// A-frag: lane holds x[r0 + (lane&15)][32c + (lane>>4)*8 + 0..7].
// B-frag: staged wt from LDS, ds_read_b128 (lane-stride 16B, conflict-free).
// C/D: col = lane&15, row = (lane>>4)*4 + reg  [learn_hip m89/m91 verified].
__global__ __launch_bounds__(256) void gemm_mfma(const float* __restrict__ x,
                                                 const unsigned short* __restrict__ wt,
                                                 unsigned short* __restrict__ hb) {
    __shared__ unsigned short wl[16384];   // 32 KB
    const int tid = threadIdx.x;
    for (int i = tid; i < 2048; i += 256)
        ((us8*)wl)[i] = ((const us8*)wt)[i];
    __syncthreads();

    const int wave = tid >> 6, lane = tid & 63;
    const long r0 = ((long)blockIdx.x * 4 + wave) * 16;   // 6252 waves, 6250 used
    if (r0 >= NODES) return;
    const int m = lane & 15, q = lane >> 4;
    const float* xr = x + (r0 + m) * D;

    f32x4 acc[8];
#pragma unroll
    for (int ct = 0; ct < 8; ct++) acc[ct] = (f32x4){0.f, 0.f, 0.f, 0.f};

#pragma unroll
    for (int c = 0; c < 4; c++) {
        const int k0 = 32 * c + 8 * q;
        float4 xa = *(const float4*)(xr + k0);
        float4 xb = *(const float4*)(xr + k0 + 4);
        bf16x8 a;
        a[0] = (short)f32_to_bf16_rn(xa.x);
        a[1] = (short)f32_to_bf16_rn(xa.y);
        a[2] = (short)f32_to_bf16_rn(xa.z);
        a[3] = (short)f32_to_bf16_rn(xa.w);
        a[4] = (short)f32_to_bf16_rn(xb.x);
        a[5] = (short)f32_to_bf16_rn(xb.y);
        a[6] = (short)f32_to_bf16_rn(xb.z);
        a[7] = (short)f32_to_bf16_rn(xb.w);
#pragma unroll
        for (int ct = 0; ct < 8; ct++) {
            bf16x8 bfr = *(const bf16x8*)&wl[(((ct << 2) + c) * 64 + lane) * 8];
            acc[ct] = __builtin_amdgcn_mfma_f32_16x16x32_bf16(a, bfr, acc[ct], 0, 0, 0);
        }
    }

#pragma unroll
    for (int ct = 0; ct < 8; ct++) {
#pragma unroll
        for (int r = 0; r < 4; r++) {
            int row = q * 4 + r;
            hb[(r0 + row) * D + ct * 16 + m] = f32_to_bf16_rn(acc[ct][r]);
        }
    }
}

// ---------------- bucket-level counting (391 bins only) ---------------------

__global__ __launch_bounds__(256) void zero_bcnt(int* __restrict__ bcnt) {
    int i = blockIdx.x * 256 + threadIdx.x;
    if (i < NBUCKET) bcnt[i] = 0;
}

__global__ __launch_bounds__(256) void bucket_hist(const int* __restrict__ edst,
                                                   int* __restrict__ bcnt) {
    __shared__ int h[NBUCKET];
    const int tid = threadIdx.x;
    for (int i = tid; i < NBUCKET; i += 256) h[i] = 0;
    __syncthreads();
    const long e0 = (long)blockIdx.x * CH;
    for (int i = tid; i < CH; i += 256) {
        long e = e0 + i;
        if (e < EDGES) atomicAdd(&h[edst[e] >> 8], 1);
    }
    __syncthreads();
    for (int i = tid; i < NBUCKET; i += 256)
        if (h[i]) atomicAdd(&bcnt[i], h[i]);
}

// single block: exclusive scan of bcnt[391] -> bbase[392]; copy into bcur
__global__ __launch_bounds__(512) void bucket_scan(const int* __restrict__ bcnt,
                                                   int* __restrict__ bbase,
                                                   int* __restrict__ bcur) {
    __shared__ int sd[512];
    int tid = threadIdx.x;
    sd[tid] = (tid < NBUCKET) ? bcnt[tid] : 0;
    __syncthreads();
#pragma unroll
    for (int off = 1; off < 512; off <<= 1) {
        int t = (tid >= off) ? sd[tid - off] : 0;
        __syncthreads();
        sd[tid] += t;
        __syncthreads();
    }
    if (tid < NBUCKET) {
        int e = (tid > 0) ? sd[tid - 1] : 0;
        bbase[tid] = e;
        bcur[tid] = e;
    }
    if (tid == 0) bbase[NBUCKET] = EDGES;
}

// ---------------- two-level binned permute ----------------------------------
// pass 1: bin edges by dst>>8 into CSR-coordinate bucket regions.
__global__ __launch_bounds__(256) void bin_pass1(const int* __restrict__ esrc,
                                                 const int* __restrict__ edst,
                                                 const float* __restrict__ eval,
                                                 int* __restrict__ bcur,
                                                 int2* __restrict__ tmp) {
    __shared__ int hist[NBUCKET];
    __shared__ int base[NBUCKET];
    __shared__ int lcur[NBUCKET];
    const int tid = threadIdx.x;
    const long e0 = (long)blockIdx.x * CH;

    for (int b = tid; b < NBUCKET; b += 256) { hist[b] = 0; lcur[b] = 0; }
    __syncthreads();
    for (int i = tid; i < CH; i += 256) {
        long e = e0 + i;
        if (e < EDGES) atomicAdd(&hist[edst[e] >> 8], 1);
    }
    __syncthreads();
    for (int b = tid; b < NBUCKET; b += 256) {
        int c = hist[b];
        if (c > 0) base[b] = atomicAdd(&bcur[b], c);
    }
    __syncthreads();
    for (int i = tid; i < CH; i += 256) {
        long e = e0 + i;
        if (e < EDGES) {
            int dst = edst[e];
            unsigned q = (unsigned)(eval[e] * 32768.0f);
            if (q > 32767u) q = 32767u;
            unsigned pk = (q << 17) | (unsigned)esrc[e];
            int bk = dst >> 8;
            int pos = base[bk] + atomicAdd(&lcur[bk], 1);
            tmp[pos] = make_int2((int)pk, dst);
        }
    }
}

// pass 2: one block per bucket. LDS 256-bin histogram + block scan gives
// per-node CSR offsets (writes rp!), then L2-local scatter into epack.
__global__ __launch_bounds__(256) void bin_pass2(const int* __restrict__ bbase,
                                                 const int2* __restrict__ tmp,
                                                 int* __restrict__ rp,
                                                 unsigned int* __restrict__ epack) {
    __shared__ int cnt[256];
    __shared__ int pos[256];
    __shared__ int wsum[4];
    const int b = blockIdx.x;
    const int tid = threadIdx.x;
    const int beg = bbase[b], end = bbase[b + 1];

    cnt[tid] = 0;
    __syncthreads();
    for (int i = beg + tid; i < end; i += 256)
        atomicAdd(&cnt[tmp[i].y & 255], 1);
    __syncthreads();

    // block-wide exclusive scan of cnt[256]
    int v = cnt[tid];
    int lane = tid & 63, wid = tid >> 6;
    int s = v;
#pragma unroll
    for (int off = 1; off < 64; off <<= 1) {
        int t = __shfl_up(s, off, 64);
        if (lane >= off) s += t;
    }
    if (lane == 63) wsum[wid] = s;
    __syncthreads();
    int base = 0;
    for (int w = 0; w < wid; w++) base += wsum[w];
    int excl = base + s - v;
    pos[tid] = excl;                        // becomes the per-node cursor
    int node = (b << 8) + tid;
    if (node < NODES) rp[node] = beg + excl;
    if (b == NBUCKET - 1 && tid == 0) rp[NODES] = EDGES;
    __syncthreads();

    for (int i = beg + tid; i < end; i += 256) {
        int2 t = tmp[i];
        int p = beg + atomicAdd(&pos[t.y & 255], 1);
        epack[p] = (unsigned)t.x;
    }
}

// ---------------- aggregation: 2 nodes/wave, bf16 h, edge-pairs -------------
__global__ __launch_bounds__(256) void aggregate(const int* __restrict__ rp,
                                                 const unsigned int* __restrict__ epack,
                                                 const unsigned short* __restrict__ hb,
                                                 const float* __restrict__ b,
                                                 float* __restrict__ out) {
    int tid = threadIdx.x;
    int node = blockIdx.x * 8 + (tid >> 5);
    if (node >= NODES) return;
    int l = tid & 31;
    int sub = l >> 4;
    int li = l & 15;
    int beg = rp[node];
    int end = rp[node + 1];

    float acc[8];
#pragma unroll
    for (int k = 0; k < 8; k++) acc[k] = 0.f;

    int e = beg;
    for (; e + 3 < end; e += 4) {
        unsigned p0 = epack[e + sub];
        unsigned p1 = epack[e + 2 + sub];
        int s0 = p0 & 0x1FFFF;
        int s1 = p1 & 0x1FFFF;
        float v0 = (float)(p0 >> 17) * (1.f / 32768.f);
        float v1 = (float)(p1 >> 17) * (1.f / 32768.f);
        us8 r0 = *(const us8*)(hb + (long)s0 * D + li * 8);
        us8 r1 = *(const us8*)(hb + (long)s1 * D + li * 8);
#pragma unroll
        for (int k = 0; k < 8; k++) {
            float f0 = __uint_as_float(((unsigned)r0[k]) << 16);
            float f1 = __uint_as_float(((unsigned)r1[k]) << 16);
            acc[k] += v0 * f0 + v1 * f1;
        }
    }
    for (; e + 1 < end; e += 2) {
        unsigned p0 = epack[e + sub];
        int s0 = p0 & 0x1FFFF;
        float v0 = (float)(p0 >> 17) * (1.f / 32768.f);
        us8 r0 = *(const us8*)(hb + (long)s0 * D + li * 8);
#pragma unroll
        for (int k = 0; k < 8; k++)
            acc[k] += v0 * __uint_as_float(((unsigned)r0[k]) << 16);
    }
    if (e < end) {                         // odd tail: both subs, half weight
        unsigned p0 = epack[e];
        int s0 = p0 & 0x1FFFF;
        float v0 = (float)(p0 >> 17) * (0.5f / 32768.f);
        us8 r0 = *(const us8*)(hb + (long)s0 * D + li * 8);
#pragma unroll
        for (int k = 0; k < 8; k++)
            acc[k] += v0 * __uint_as_float(((unsigned)r0[k]) << 16);
    }

#pragma unroll
    for (int k = 0; k < 8; k++) acc[k] += __shfl_xor(acc[k], 16, 64);

    int c0 = li * 8 + sub * 4;
    float4 bv = *(const float4*)(b + c0);
    float4 o;
    o.x = fmaxf(acc[sub * 4 + 0] + bv.x, 0.f);
    o.y = fmaxf(acc[sub * 4 + 1] + bv.y, 0.f);
    o.z = fmaxf(acc[sub * 4 + 2] + bv.z, 0.f);
    o.w = fmaxf(acc[sub * 4 + 3] + bv.w, 0.f);
    *(float4*)(out + (long)node * D + c0) = o;
}

extern "C" void kernel_launch(void* const* d_in, const int* in_sizes, int n_in,
                              void* d_out, int out_size, void* d_ws, size_t ws_size,
                              hipStream_t stream) {
    const float* x    = (const float*)d_in[0];
    const int*   esrc = (const int*)  d_in[1];
    const int*   edst = (const int*)  d_in[2];
    const float* eval = (const float*)d_in[3];
    const float* w    = (const float*)d_in[4];
    const float* b    = (const float*)d_in[5];
    float* out = (float*)d_out;

    // workspace layout (bytes), total ~64.5 MB
    char* ws = (char*)d_ws;
    const size_t OFF_H    = 0;                       // 25,600,000 (bf16 h)
    const size_t OFF_WT   = 25600000;                // 32,768 (bf16 wt)
    const size_t OFF_RP   = OFF_WT   + 32768;        // 400,004 -> pad 400,064
    const size_t OFF_BCNT = OFF_RP   + 400064;       // 2048
    const size_t OFF_BBAS = OFF_BCNT + 2048;         // 2048
    const size_t OFF_BCUR = OFF_BBAS + 2048;         // 2048
    const size_t OFF_TMP  = OFF_BCUR + 2048;         // 25,600,000 (int2)
    const size_t OFF_EPK  = OFF_TMP  + 25600000;     // 12,800,000

    unsigned short* hb    = (unsigned short*)(ws + OFF_H);
    unsigned short* wt    = (unsigned short*)(ws + OFF_WT);
    int*            rp    = (int*)           (ws + OFF_RP);
    int*            bcnt  = (int*)           (ws + OFF_BCNT);
    int*            bbase = (int*)           (ws + OFF_BBAS);
    int*            bcur  = (int*)           (ws + OFF_BCUR);
    int2*           tmp   = (int2*)          (ws + OFF_TMP);
    unsigned int*   epack = (unsigned int*)  (ws + OFF_EPK);

    wprep<<<64, 256, 0, stream>>>(w, wt);
    gemm_mfma<<<(NODES + 63) / 64, 256, 0, stream>>>(x, wt, hb);
    zero_bcnt<<<2, 256, 0, stream>>>(bcnt);
    bucket_hist<<<NB_BIN, 256, 0, stream>>>(edst, bcnt);
    bucket_scan<<<1, 512, 0, stream>>>(bcnt, bbase, bcur);
    bin_pass1<<<NB_BIN, 256, 0, stream>>>(esrc, edst, eval, bcur, tmp);
    bin_pass2<<<NBUCKET, 256, 0, stream>>>(bbase, tmp, rp, epack);
    aggregate<<<(NODES + 7) / 8, 256, 0, stream>>>(rp, epack, hb, b, out);
}